// Round 22
// baseline (440.231 us; speedup 1.0000x reference)
//
#include <hip/hip_runtime.h>
#include <hip/hip_bf16.h>
#include <stdint.h>

#define S_LEN 4096
#define D_DIM 1024
#define N_HEADS 16
#define DK_DIM 64
#define B_SZ 4
#define N_TOK (B_SZ * S_LEN)

typedef __attribute__((ext_vector_type(8))) short short8;
typedef __attribute__((ext_vector_type(4))) short shortx4;
typedef __attribute__((ext_vector_type(4))) float f32x4;

#define AS1 __attribute__((address_space(1)))
#define AS3 __attribute__((address_space(3)))

__device__ __forceinline__ float b2f(short u) {
  union { unsigned int i; float f; } c;
  c.i = ((unsigned int)(unsigned short)u) << 16;
  return c.f;
}
__device__ __forceinline__ short f2b(float f) {
  union { float f; unsigned int i; } c;
  c.f = f;
  unsigned int i = c.i + 0x7FFFu + ((c.i >> 16) & 1u);
  return (short)(i >> 16);
}

// ONE launch converts: 7 weight matrices (blocks 0..7167), query (7168..
// 23551), key (23552..39935), and optionally value (39936..56319, only
// when launched with grid 56320 and ABv != null).  1024 elems per block.
__global__ __launch_bounds__(256)
void cvt_all(const float* __restrict__ s0, const float* __restrict__ s1,
             const float* __restrict__ s2, const float* __restrict__ s3,
             const float* __restrict__ s4, const float* __restrict__ s5,
             const float* __restrict__ s6, short* __restrict__ WB,
             const float* __restrict__ q, short* __restrict__ ABq,
             const float* __restrict__ k, short* __restrict__ ABk,
             const float* __restrict__ v, short* __restrict__ ABv)
{
  const int bid = blockIdx.x;
  const float* src;
  short* dst;
  size_t base;
  if (bid < 7168) {
    const float* srcs[7] = {s0, s1, s2, s3, s4, s5, s6};
    const int m = bid >> 10;
    src = srcs[m];
    dst = WB + (size_t)m * D_DIM * D_DIM;
    base = (size_t)(bid & 1023) * 1024 + threadIdx.x * 4;
  } else if (bid < 23552) {
    src = q; dst = ABq;
    base = (size_t)(bid - 7168) * 1024 + threadIdx.x * 4;
  } else if (bid < 39936) {
    src = k; dst = ABk;
    base = (size_t)(bid - 23552) * 1024 + threadIdx.x * 4;
  } else {
    src = v; dst = ABv;
    base = (size_t)(bid - 39936) * 1024 + threadIdx.x * 4;
  }
  f32x4 vv = *(const f32x4*)(src + base);
  shortx4 o;
#pragma unroll
  for (int j = 0; j < 4; ++j) o[j] = f2b(vv[j]);
  *(shortx4*)(dst + base) = o;
}

// fp32 -> bf16 activation conversion (16384 blocks) — fallback path only.
__global__ __launch_bounds__(256)
void cvt_a(const float* __restrict__ src, short* __restrict__ dst)
{
  const int i = (blockIdx.x * 256 + threadIdx.x) * 4;
  f32x4 v = *(const f32x4*)(src + i);
  shortx4 o;
#pragma unroll
  for (int j = 0; j < 4; ++j) o[j] = f2b(v[j]);
  *(shortx4*)(dst + i) = o;
}

// Dual-accumulator 256x128 GEMM for the fused GLU projections (banked):
// u = A@W1^T + b1 (fp32, in-register), g = A@W2^T + b2, out = act(u,g).
// Counted-vmcnt double-buffer: BK=64, 8 waves (2x4), 512 thr, LDS 128 KiB,
// 8 loads/thread/tile -> vmcnt(8).  Both-sides chunk-XOR swizzle.
// MODE 1: out = silu(u)*g; MODE 2: elu(.)+1; MODE 3: MODE2 * mask[row].
template<int MODE>
__global__ __launch_bounds__(512)
void gemm_dual(const short* __restrict__ A, const short* __restrict__ W1,
               const float* __restrict__ b1v, const short* __restrict__ W2,
               const float* __restrict__ b2v, const float* __restrict__ mask,
               short* __restrict__ Out)
{
  __shared__ short lsA[2][256 * 64];
  __shared__ short lsW1[2][128 * 64];
  __shared__ short lsW2[2][128 * 64];
  const int t = threadIdx.x;            // 0..511
  const int lane = t & 63, w = t >> 6;  // 8 waves
  const int wr = w >> 2, wc = w & 3;    // 2 x 4 wave grid; wave out 128x32
  const int fr = lane & 15;
  const int kq = lane >> 4;
  const int cswz = fr & 7;
  // XCD swizzle: nwg=512, 512%8==0 -> XCD x gets bm in [x*8, x*8+8).
  const int orig = blockIdx.x;
  const int swz = (orig & 7) * 64 + (orig >> 3);
  const int bn = swz & 7, bm = swz >> 3;

  const f32x4 z4 = {0.f, 0.f, 0.f, 0.f};
  f32x4 acc1[8][2], acc2[8][2];
#pragma unroll
  for (int m = 0; m < 8; ++m)
#pragma unroll
    for (int n = 0; n < 2; ++n) { acc1[m][n] = z4; acc2[m][n] = z4; }

  const short* Ab  = A  + (size_t)bm * 256 * D_DIM;
  const short* W1b = W1 + (size_t)bn * 128 * D_DIM;
  const short* W2b = W2 + (size_t)bn * 128 * D_DIM;

  // A: 2048 chunks -> 4/thread; W1/W2: 1024 chunks -> 2/thread. 8 total.
#define STAGE_DUAL(bi, ks)                                                   \
  {                                                                          \
    _Pragma("unroll")                                                        \
    for (int p = 0; p < 4; ++p) {                                            \
      const int idx = p * 512 + t;                                           \
      const int row = idx >> 3;                                              \
      const int cs = (idx & 7) ^ (row & 7);                                  \
      const size_t off = (size_t)row * D_DIM + (ks) * 64 + (cs << 3);        \
      __builtin_amdgcn_global_load_lds((const AS1 void*)(Ab + off),          \
          (AS3 void*)((AS3 short*)&lsA[bi][0] + idx * 8), 16, 0, 0);         \
    }                                                                        \
    _Pragma("unroll")                                                        \
    for (int p = 0; p < 2; ++p) {                                            \
      const int idx = p * 512 + t;                                           \
      const int row = idx >> 3;                                              \
      const int cs = (idx & 7) ^ (row & 7);                                  \
      const size_t off = (size_t)row * D_DIM + (ks) * 64 + (cs << 3);        \
      __builtin_amdgcn_global_load_lds((const AS1 void*)(W1b + off),         \
          (AS3 void*)((AS3 short*)&lsW1[bi][0] + idx * 8), 16, 0, 0);        \
      __builtin_amdgcn_global_load_lds((const AS1 void*)(W2b + off),         \
          (AS3 void*)((AS3 short*)&lsW2[bi][0] + idx * 8), 16, 0, 0);        \
    }                                                                        \
  }

  STAGE_DUAL(0, 0);
  for (int ks = 0; ks < 16; ++ks) {
    const int cur = ks & 1;
    if (ks + 1 < 16) {
      STAGE_DUAL(cur ^ 1, ks + 1);
      // tile ks's 8 loads are the oldest; leave tile ks+1's 8 in flight.
      asm volatile("s_waitcnt vmcnt(8)" ::: "memory");
    } else {
      asm volatile("s_waitcnt vmcnt(0)" ::: "memory");
    }
    __builtin_amdgcn_s_barrier();         // all waves: buf[cur] ready
    __builtin_amdgcn_sched_barrier(0);
#pragma unroll
    for (int kk = 0; kk < 64; kk += 32) {
      const int cb = kk >> 3;
      const int pch = ((cb + kq) ^ cswz) << 3;
      short8 g1[2], g2[2];
#pragma unroll
      for (int n = 0; n < 2; ++n) {
        const int ro = (wc * 32 + n * 16 + fr) * 64 + pch;
        g1[n] = *(const short8*)&lsW1[cur][ro];
        g2[n] = *(const short8*)&lsW2[cur][ro];
      }
#pragma unroll
      for (int m = 0; m < 8; ++m) {
        short8 af = *(const short8*)
            &lsA[cur][(wr * 128 + m * 16 + fr) * 64 + pch];
#pragma unroll
        for (int n = 0; n < 2; ++n) {
          acc1[m][n] = __builtin_amdgcn_mfma_f32_16x16x32_bf16(
              af, g1[n], acc1[m][n], 0, 0, 0);
          acc2[m][n] = __builtin_amdgcn_mfma_f32_16x16x32_bf16(
              af, g2[n], acc2[m][n], 0, 0, 0);
        }
      }
    }
    __builtin_amdgcn_sched_barrier(0);    // keep reads above the barrier
    __builtin_amdgcn_s_barrier();         // reads done; next STAGE may write
  }
#undef STAGE_DUAL

  // Epilogue: native C/D layout (col=lane&15, row=(lane>>4)*4+i); u,g fused.
  const int hi4 = (lane >> 4) << 2;
#pragma unroll
  for (int m = 0; m < 8; ++m) {
    const int grow0 = bm * 256 + wr * 128 + m * 16 + hi4;
#pragma unroll
    for (int n = 0; n < 2; ++n) {
      const int gcol = bn * 128 + wc * 32 + n * 16 + fr;
      const float bb1 = b1v[gcol];
      const float bb2 = b2v[gcol];
#pragma unroll
      for (int i = 0; i < 4; ++i) {
        float u = acc1[m][n][i] + bb1;
        float g = acc2[m][n][i] + bb2;
        float r = (u / (1.f + __expf(-u))) * g;   // silu(u)*g
        if (MODE >= 2) r = (r > 0.f) ? (r + 1.f) : __expf(r);  // elu+1
        if (MODE == 3) r *= mask[grow0 + i];
        Out[(size_t)(grow0 + i) * D_DIM + gcol] = f2b(r);
      }
    }
  }
}

// 256x256-tile single GEMM (banked) — output projection only.
// MODE 0: out fp32 = acc + bias.
template<int MODE>
__global__ __launch_bounds__(512)
void gemm256(const short* __restrict__ A, const short* __restrict__ W,
             const float* __restrict__ bias, const short* __restrict__ U,
             const float* __restrict__ mask, void* __restrict__ OutV)
{
  __shared__ short lsA[2][256 * 64];
  __shared__ short lsB[2][256 * 64];
  const int t = threadIdx.x;            // 0..511
  const int lane = t & 63, w = t >> 6;  // 8 waves
  const int wr = w >> 2, wc = w & 3;    // 2 x 4 wave grid
  const int fr = lane & 15;
  const int kq = lane >> 4;
  const int cswz = fr & 7;
  const int orig = blockIdx.x;
  const int swz = (orig & 7) * 32 + (orig >> 3);
  const int bn = swz & 3, bm = swz >> 2;

  const f32x4 z4 = {0.f, 0.f, 0.f, 0.f};
  f32x4 acc[8][4];
#pragma unroll
  for (int m = 0; m < 8; ++m)
#pragma unroll
    for (int n = 0; n < 4; ++n) acc[m][n] = z4;

  const short* Ab = A + (size_t)bm * 256 * D_DIM;
  const short* Wb = W + (size_t)bn * 256 * D_DIM;

#define STAGE256(bi, ks)                                                     \
  {                                                                          \
    _Pragma("unroll")                                                        \
    for (int p = 0; p < 4; ++p) {                                            \
      const int idx = p * 512 + t;                                           \
      const int row = idx >> 3;                                              \
      const int cs = (idx & 7) ^ (row & 7);                                  \
      const size_t off = (size_t)row * D_DIM + (ks) * 64 + (cs << 3);        \
      __builtin_amdgcn_global_load_lds((const AS1 void*)(Ab + off),          \
          (AS3 void*)((AS3 short*)&lsA[bi][0] + idx * 8), 16, 0, 0);         \
      __builtin_amdgcn_global_load_lds((const AS1 void*)(Wb + off),          \
          (AS3 void*)((AS3 short*)&lsB[bi][0] + idx * 8), 16, 0, 0);         \
    }                                                                        \
  }

  STAGE256(0, 0);
  for (int ks = 0; ks < 16; ++ks) {
    const int cur = ks & 1;
    if (ks + 1 < 16) {
      STAGE256(cur ^ 1, ks + 1);
      asm volatile("s_waitcnt vmcnt(8)" ::: "memory");
    } else {
      asm volatile("s_waitcnt vmcnt(0)" ::: "memory");
    }
    __builtin_amdgcn_s_barrier();
    __builtin_amdgcn_sched_barrier(0);
#pragma unroll
    for (int kk = 0; kk < 64; kk += 32) {
      const int cb = kk >> 3;
      const int pch = ((cb + kq) ^ cswz) << 3;
      short8 bfrag[4];
#pragma unroll
      for (int n = 0; n < 4; ++n)
        bfrag[n] = *(const short8*)&lsB[cur][(wc * 64 + n * 16 + fr) * 64 + pch];
#pragma unroll
      for (int m = 0; m < 8; ++m) {
        short8 af = *(const short8*)&lsA[cur][(wr * 128 + m * 16 + fr) * 64 + pch];
#pragma unroll
        for (int n = 0; n < 4; ++n)
          acc[m][n] = __builtin_amdgcn_mfma_f32_16x16x32_bf16(
              af, bfrag[n], acc[m][n], 0, 0, 0);
      }
    }
    __builtin_amdgcn_sched_barrier(0);
    __builtin_amdgcn_s_barrier();
  }
#undef STAGE256

  const int hi4 = (lane >> 4) << 2;
#pragma unroll
  for (int m = 0; m < 8; ++m) {
    const int grow0 = bm * 256 + wr * 128 + m * 16 + hi4;
#pragma unroll
    for (int n = 0; n < 4; ++n) {
      const int gcol = bn * 256 + wc * 64 + n * 16 + fr;
      const float bb = bias[gcol];
#pragma unroll
      for (int i = 0; i < 4; ++i) {
        const size_t o = (size_t)(grow0 + i) * D_DIM + gcol;
        if (MODE == 0) {
          ((float*)OutV)[o] = acc[m][n][i] + bb;
        } else {
          float g = acc[m][n][i] + bb;
          float u = b2f(U[o]);
          float r = (u / (1.f + __expf(-u))) * g;
          if (MODE >= 2) r = (r > 0.f) ? (r + 1.f) : __expf(r);
          if (MODE == 3) r *= mask[grow0 + i];
          ((short*)OutV)[o] = f2b(r);
        }
      }
    }
  }
}

// kv[bh] += phi_k[s,:].outer(v[s,:]) over an s-chunk of 512; also ksum.
// 64-row chunks + wave-parallel ksum (banked).
__global__ __launch_bounds__(256)
void kv_partial(const short* __restrict__ PK, const short* __restrict__ PV,
                float* __restrict__ KVP, float* __restrict__ KSP)
{
  __shared__ float lsK[64 * 68];
  __shared__ float lsV[64 * 68];
  __shared__ float lsS[256];
  const int t = threadIdx.x;
  const int bh = blockIdx.x;               // 0..63
  const int b = bh >> 4, h = bh & 15;
  const int s0 = blockIdx.y * 512;         // 8 chunks
  const int r0 = (t >> 4) * 4, c0 = (t & 15) * 4;
  const int srow = t >> 3, d0 = (t & 7) * 8;
  const int kc = t & 63, kr0 = (t >> 6) * 16;
  float acc[4][4] = {{0.f}};
  float ks = 0.f;
  const size_t gbase = ((size_t)b * S_LEN + s0 + srow) * D_DIM + h * DK_DIM + d0;
  for (int sc = 0; sc < 512; sc += 64) {
    const size_t g = gbase + (size_t)sc * D_DIM;
    short8 rk0 = *(const short8*)(PK + g);
    short8 rv0 = *(const short8*)(PV + g);
    short8 rk1 = *(const short8*)(PK + g + (size_t)32 * D_DIM);
    short8 rv1 = *(const short8*)(PV + g + (size_t)32 * D_DIM);
    __syncthreads();   // prior chunk's readers (incl. ksum) done
#pragma unroll
    for (int j = 0; j < 8; ++j) {
      lsK[srow * 68 + d0 + j] = b2f(rk0[j]);
      lsV[srow * 68 + d0 + j] = b2f(rv0[j]);
      lsK[(srow + 32) * 68 + d0 + j] = b2f(rk1[j]);
      lsV[(srow + 32) * 68 + d0 + j] = b2f(rv1[j]);
    }
    __syncthreads();
#pragma unroll 8
    for (int s = 0; s < 64; ++s) {
      f32x4 ak = *(const f32x4*)&lsK[s * 68 + r0];
      f32x4 av = *(const f32x4*)&lsV[s * 68 + c0];
#pragma unroll
      for (int i = 0; i < 4; ++i)
#pragma unroll
        for (int j = 0; j < 4; ++j) acc[i][j] += ak[i] * av[j];
    }
#pragma unroll
    for (int i = 0; i < 16; ++i) ks += lsK[(kr0 + i) * 68 + kc];
  }
  const size_t po = ((size_t)bh * 8 + blockIdx.y) * 4096;
#pragma unroll
  for (int i = 0; i < 4; ++i)
#pragma unroll
    for (int j = 0; j < 4; ++j)
      KVP[po + (size_t)(r0 + i) * 64 + c0 + j] = acc[i][j];
  lsS[t] = ks;
  __syncthreads();
  if (t < 64)
    KSP[((size_t)bh * 8 + blockIdx.y) * 64 + t] =
        lsS[t] + lsS[64 + t] + lsS[128 + t] + lsS[192 + t];
}

__global__ __launch_bounds__(256)
void kv_reduce(const float* __restrict__ KVP, const float* __restrict__ KSP,
               float* __restrict__ KV, float* __restrict__ KS)
{
  const int bh = blockIdx.x;
  const int t = threadIdx.x;
#pragma unroll
  for (int c = 0; c < 4; ++c) {
    f32x4 a = {0.f, 0.f, 0.f, 0.f};
    for (int p = 0; p < 8; ++p)
      a += *(const f32x4*)&KVP[((size_t)bh * 8 + p) * 4096 + t * 16 + c * 4];
    *(f32x4*)&KV[(size_t)bh * 4096 + t * 16 + c * 4] = a;
  }
  if (t < 64) {
    float a = 0.f;
    for (int p = 0; p < 8; ++p) a += KSP[((size_t)bh * 8 + p) * 64 + t];
    KS[(size_t)bh * 64 + t] = a;
  }
}

// attn[s,:] = (phi_q[s,:] @ kv) / (phi_q[s,:].ksum + eps); 64 s-rows/block.
__global__ __launch_bounds__(256)
void attn_k(const short* __restrict__ PQ, const float* __restrict__ KV,
            const float* __restrict__ KS, short* __restrict__ ATT)
{
  __shared__ float lsKV[4096];
  __shared__ float lsQ[64 * 65];
  __shared__ float lsS[64];
  const int t = threadIdx.x;
  const int bh = blockIdx.x >> 6;
  const int ch = blockIdx.x & 63;
  const int b = bh >> 4, h = bh & 15;
  const int s0 = ch * 64;
#pragma unroll
  for (int c = 0; c < 4; ++c)
    *(f32x4*)&lsKV[t * 16 + c * 4] =
        *(const f32x4*)&KV[(size_t)bh * 4096 + t * 16 + c * 4];
  if (t < 64) lsS[t] = KS[(size_t)bh * 64 + t];
  const int qr = t >> 2, qd = (t & 3) * 16;
  const size_t gq = ((size_t)b * S_LEN + s0 + qr) * D_DIM + h * DK_DIM + qd;
  short8 q0 = *(const short8*)(PQ + gq);
  short8 q1 = *(const short8*)(PQ + gq + 8);
#pragma unroll
  for (int j = 0; j < 8; ++j) {
    lsQ[qr * 65 + qd + j] = b2f(q0[j]);
    lsQ[qr * 65 + qd + 8 + j] = b2f(q1[j]);
  }
  __syncthreads();
  float num[16] = {0.f};
  float z = 0.f;
#pragma unroll 4
  for (int k = 0; k < 64; ++k) {
    const float q = lsQ[qr * 65 + k];
    z += q * lsS[k];
#pragma unroll
    for (int c = 0; c < 4; ++c) {
      f32x4 kv4 = *(const f32x4*)&lsKV[k * 64 + qd + c * 4];
#pragma unroll
      for (int j = 0; j < 4; ++j) num[c * 4 + j] += q * kv4[j];
    }
  }
  const float inv = 1.f / (z + 1e-6f);
  short8 o0, o1;
#pragma unroll
  for (int j = 0; j < 8; ++j) {
    o0[j] = f2b(num[j] * inv);
    o1[j] = f2b(num[j + 8] * inv);
  }
  short* op = ATT + gq;
  *(short8*)op = o0;
  *(short8*)(op + 8) = o1;
}

extern "C" void kernel_launch(void* const* d_in, const int* in_sizes, int n_in,
                              void* d_out, int out_size, void* d_ws, size_t ws_size,
                              hipStream_t stream)
{
  (void)in_sizes; (void)n_in; (void)out_size;
  const float* query = (const float*)d_in[0];
  const float* key   = (const float*)d_in[1];
  const float* value = (const float*)d_in[2];
  const float* maskp = (const float*)d_in[3];
  const float* q_w1 = (const float*)d_in[4];
  const float* q_b1 = (const float*)d_in[5];
  const float* q_w2 = (const float*)d_in[6];
  const float* q_b2 = (const float*)d_in[7];
  const float* k_w1 = (const float*)d_in[8];
  const float* k_b1 = (const float*)d_in[9];
  const float* k_w2 = (const float*)d_in[10];
  const float* k_b2 = (const float*)d_in[11];
  const float* v_w1 = (const float*)d_in[12];
  const float* v_b1 = (const float*)d_in[13];
  const float* v_w2 = (const float*)d_in[14];
  const float* v_b2 = (const float*)d_in[15];
  const float* out_w = (const float*)d_in[16];
  const float* out_b = (const float*)d_in[17];

  // Base workspace layout (87.1 MiB, banked).
  char* ws = (char*)d_ws;
  const size_t ACT = (size_t)N_TOK * D_DIM * sizeof(short);     // 32 MiB
  const size_t WSZ = (size_t)D_DIM * D_DIM * sizeof(short);     // 2 MiB
  short* PHIK = (short*)(ws);
  short* Vbuf = (short*)(ws + ACT);
  float* KVP  = (float*)(ws + 2 * ACT);                          // 8 MiB
  float* KSP  = (float*)(ws + 2 * ACT + 8388608);                // 128 KiB
  float* KV   = (float*)(ws + 2 * ACT + 8388608 + 131072);       // 1 MiB
  float* KS   = (float*)(ws + 2 * ACT + 8388608 + 131072 + 1048576); // 16 KiB
  short* WB   = (short*)(ws + 2 * ACT + 8388608 + 131072 + 1048576 + 16384);
  short* wq1 = WB;                 short* wq2 = WB + 1 * (WSZ / 2);
  short* wk1 = WB + 2 * (WSZ / 2); short* wk2 = WB + 3 * (WSZ / 2);
  short* wv1 = WB + 4 * (WSZ / 2); short* wv2 = WB + 5 * (WSZ / 2);
  short* wout = WB + 6 * (WSZ / 2);
  const size_t BASE_END = 2 * ACT + 8388608 + 131072 + 1048576 + 16384
                          + 7 * WSZ;                  // 91,373,568 B
  // Aliasing (banked): ABq = d_out upper (dead after dual(q));
  // ABk = Vbuf (dead after dual(k)); PHIQ = d_out lower; ATT = Vbuf.
  short* PHIQ = (short*)d_out;
  short* ABq  = (short*)d_out + (size_t)N_TOK * D_DIM;
  short* ABk  = Vbuf;
  short* ATT  = Vbuf;

  // If the workspace has room, give value its own staging buffer so ALL
  // conversions fold into one launch and the duals run back-to-back.
  const bool big_ws = (ws_size >= BASE_END + ACT);
  short* ABv = big_ws ? (short*)(ws + BASE_END) : ABq;

  dim3 gb(256);
  if (big_ws) {
    cvt_all<<<56320, gb, 0, stream>>>(q_w1, q_w2, k_w1, k_w2, v_w1, v_w2,
                                      out_w, WB, query, ABq, key, ABk,
                                      value, ABv);
    gemm_dual<2><<<512, 512, 0, stream>>>(ABq, wq1, q_b1, wq2, q_b2,
                                          nullptr, PHIQ);
    gemm_dual<3><<<512, 512, 0, stream>>>(ABk, wk1, k_b1, wk2, k_b2,
                                          maskp, PHIK);
    gemm_dual<1><<<512, 512, 0, stream>>>(ABv, wv1, v_b1, wv2, v_b2,
                                          nullptr, Vbuf);
  } else {
    // Fallback = round-21 exact topology.
    cvt_all<<<39936, gb, 0, stream>>>(q_w1, q_w2, k_w1, k_w2, v_w1, v_w2,
                                      out_w, WB, query, ABq, key, ABk,
                                      nullptr, nullptr);
    gemm_dual<2><<<512, 512, 0, stream>>>(ABq, wq1, q_b1, wq2, q_b2,
                                          nullptr, PHIQ);
    gemm_dual<3><<<512, 512, 0, stream>>>(ABk, wk1, k_b1, wk2, k_b2,
                                          maskp, PHIK);
    cvt_a<<<16384, gb, 0, stream>>>(value, ABv);
    gemm_dual<1><<<512, 512, 0, stream>>>(ABv, wv1, v_b1, wv2, v_b2,
                                          nullptr, Vbuf);
  }
  // linear attention core
  kv_partial<<<dim3(64, 8), gb, 0, stream>>>(PHIK, Vbuf, KVP, KSP);
  kv_reduce<<<64, gb, 0, stream>>>(KVP, KSP, KV, KS);
  attn_k<<<4096, gb, 0, stream>>>(PHIQ, KV, KS, ATT);
  // output projection (fp32 out)
  gemm256<0><<<256, 512, 0, stream>>>(ATT, wout, out_b, nullptr, nullptr,
                                      (float*)d_out);
}

// Round 23
// 419.664 us; speedup vs baseline: 1.0490x; 1.0490x over previous
//
#include <hip/hip_runtime.h>
#include <hip/hip_bf16.h>
#include <stdint.h>

#define S_LEN 4096
#define D_DIM 1024
#define N_HEADS 16
#define DK_DIM 64
#define B_SZ 4
#define N_TOK (B_SZ * S_LEN)

typedef __attribute__((ext_vector_type(8))) short short8;
typedef __attribute__((ext_vector_type(4))) short shortx4;
typedef __attribute__((ext_vector_type(4))) float f32x4;

#define AS1 __attribute__((address_space(1)))
#define AS3 __attribute__((address_space(3)))

__device__ __forceinline__ float b2f(short u) {
  union { unsigned int i; float f; } c;
  c.i = ((unsigned int)(unsigned short)u) << 16;
  return c.f;
}
__device__ __forceinline__ short f2b(float f) {
  union { float f; unsigned int i; } c;
  c.f = f;
  unsigned int i = c.i + 0x7FFFu + ((c.i >> 16) & 1u);
  return (short)(i >> 16);
}

// ONE launch converts: 7 weight matrices (blocks 0..7167), query (7168..
// 23551), key (23552..39935).  1024 fp32->bf16 elems per block.
__global__ __launch_bounds__(256)
void cvt_all(const float* __restrict__ s0, const float* __restrict__ s1,
             const float* __restrict__ s2, const float* __restrict__ s3,
             const float* __restrict__ s4, const float* __restrict__ s5,
             const float* __restrict__ s6, short* __restrict__ WB,
             const float* __restrict__ q, short* __restrict__ ABq,
             const float* __restrict__ k, short* __restrict__ ABk)
{
  const int bid = blockIdx.x;
  const float* src;
  short* dst;
  size_t base;
  if (bid < 7168) {
    const float* srcs[7] = {s0, s1, s2, s3, s4, s5, s6};
    const int m = bid >> 10;
    src = srcs[m];
    dst = WB + (size_t)m * D_DIM * D_DIM;
    base = (size_t)(bid & 1023) * 1024 + threadIdx.x * 4;
  } else if (bid < 23552) {
    src = q; dst = ABq;
    base = (size_t)(bid - 7168) * 1024 + threadIdx.x * 4;
  } else {
    src = k; dst = ABk;
    base = (size_t)(bid - 23552) * 1024 + threadIdx.x * 4;
  }
  f32x4 v = *(const f32x4*)(src + base);
  shortx4 o;
#pragma unroll
  for (int j = 0; j < 4; ++j) o[j] = f2b(v[j]);
  *(shortx4*)(dst + base) = o;
}

// fp32 -> bf16 activation conversion (16384 blocks) — value only (its
// destination buffer is freed by gemm_dual<2>).
__global__ __launch_bounds__(256)
void cvt_a(const float* __restrict__ src, short* __restrict__ dst)
{
  const int i = (blockIdx.x * 256 + threadIdx.x) * 4;
  f32x4 v = *(const f32x4*)(src + i);
  shortx4 o;
#pragma unroll
  for (int j = 0; j < 4; ++j) o[j] = f2b(v[j]);
  *(shortx4*)(dst + i) = o;
}

// Dual-accumulator 256x128 GEMM for the fused GLU projections (banked):
// u = A@W1^T + b1 (fp32, in-register), g = A@W2^T + b2, out = act(u,g).
// Counted-vmcnt double-buffer: BK=64, 8 waves (2x4), 512 thr, LDS 128 KiB,
// 8 loads/thread/tile -> vmcnt(8).  Both-sides chunk-XOR swizzle.
// MODE 1: out = silu(u)*g; MODE 2: elu(.)+1; MODE 3: MODE2 * mask[row].
template<int MODE>
__global__ __launch_bounds__(512)
void gemm_dual(const short* __restrict__ A, const short* __restrict__ W1,
               const float* __restrict__ b1v, const short* __restrict__ W2,
               const float* __restrict__ b2v, const float* __restrict__ mask,
               short* __restrict__ Out)
{
  __shared__ short lsA[2][256 * 64];
  __shared__ short lsW1[2][128 * 64];
  __shared__ short lsW2[2][128 * 64];
  const int t = threadIdx.x;            // 0..511
  const int lane = t & 63, w = t >> 6;  // 8 waves
  const int wr = w >> 2, wc = w & 3;    // 2 x 4 wave grid; wave out 128x32
  const int fr = lane & 15;
  const int kq = lane >> 4;
  const int cswz = fr & 7;
  // XCD swizzle: nwg=512, 512%8==0 -> XCD x gets bm in [x*8, x*8+8).
  const int orig = blockIdx.x;
  const int swz = (orig & 7) * 64 + (orig >> 3);
  const int bn = swz & 7, bm = swz >> 3;

  const f32x4 z4 = {0.f, 0.f, 0.f, 0.f};
  f32x4 acc1[8][2], acc2[8][2];
#pragma unroll
  for (int m = 0; m < 8; ++m)
#pragma unroll
    for (int n = 0; n < 2; ++n) { acc1[m][n] = z4; acc2[m][n] = z4; }

  const short* Ab  = A  + (size_t)bm * 256 * D_DIM;
  const short* W1b = W1 + (size_t)bn * 128 * D_DIM;
  const short* W2b = W2 + (size_t)bn * 128 * D_DIM;

  // A: 2048 chunks -> 4/thread; W1/W2: 1024 chunks -> 2/thread. 8 total.
#define STAGE_DUAL(bi, ks)                                                   \
  {                                                                          \
    _Pragma("unroll")                                                        \
    for (int p = 0; p < 4; ++p) {                                            \
      const int idx = p * 512 + t;                                           \
      const int row = idx >> 3;                                              \
      const int cs = (idx & 7) ^ (row & 7);                                  \
      const size_t off = (size_t)row * D_DIM + (ks) * 64 + (cs << 3);        \
      __builtin_amdgcn_global_load_lds((const AS1 void*)(Ab + off),          \
          (AS3 void*)((AS3 short*)&lsA[bi][0] + idx * 8), 16, 0, 0);         \
    }                                                                        \
    _Pragma("unroll")                                                        \
    for (int p = 0; p < 2; ++p) {                                            \
      const int idx = p * 512 + t;                                           \
      const int row = idx >> 3;                                              \
      const int cs = (idx & 7) ^ (row & 7);                                  \
      const size_t off = (size_t)row * D_DIM + (ks) * 64 + (cs << 3);        \
      __builtin_amdgcn_global_load_lds((const AS1 void*)(W1b + off),         \
          (AS3 void*)((AS3 short*)&lsW1[bi][0] + idx * 8), 16, 0, 0);        \
      __builtin_amdgcn_global_load_lds((const AS1 void*)(W2b + off),         \
          (AS3 void*)((AS3 short*)&lsW2[bi][0] + idx * 8), 16, 0, 0);        \
    }                                                                        \
  }

  STAGE_DUAL(0, 0);
  for (int ks = 0; ks < 16; ++ks) {
    const int cur = ks & 1;
    if (ks + 1 < 16) {
      STAGE_DUAL(cur ^ 1, ks + 1);
      // tile ks's 8 loads are the oldest; leave tile ks+1's 8 in flight.
      asm volatile("s_waitcnt vmcnt(8)" ::: "memory");
    } else {
      asm volatile("s_waitcnt vmcnt(0)" ::: "memory");
    }
    __builtin_amdgcn_s_barrier();         // all waves: buf[cur] ready
    __builtin_amdgcn_sched_barrier(0);
#pragma unroll
    for (int kk = 0; kk < 64; kk += 32) {
      const int cb = kk >> 3;
      const int pch = ((cb + kq) ^ cswz) << 3;
      short8 g1[2], g2[2];
#pragma unroll
      for (int n = 0; n < 2; ++n) {
        const int ro = (wc * 32 + n * 16 + fr) * 64 + pch;
        g1[n] = *(const short8*)&lsW1[cur][ro];
        g2[n] = *(const short8*)&lsW2[cur][ro];
      }
#pragma unroll
      for (int m = 0; m < 8; ++m) {
        short8 af = *(const short8*)
            &lsA[cur][(wr * 128 + m * 16 + fr) * 64 + pch];
#pragma unroll
        for (int n = 0; n < 2; ++n) {
          acc1[m][n] = __builtin_amdgcn_mfma_f32_16x16x32_bf16(
              af, g1[n], acc1[m][n], 0, 0, 0);
          acc2[m][n] = __builtin_amdgcn_mfma_f32_16x16x32_bf16(
              af, g2[n], acc2[m][n], 0, 0, 0);
        }
      }
    }
    __builtin_amdgcn_sched_barrier(0);    // keep reads above the barrier
    __builtin_amdgcn_s_barrier();         // reads done; next STAGE may write
  }
#undef STAGE_DUAL

  // Epilogue: native C/D layout (col=lane&15, row=(lane>>4)*4+i); u,g fused.
  const int hi4 = (lane >> 4) << 2;
#pragma unroll
  for (int m = 0; m < 8; ++m) {
    const int grow0 = bm * 256 + wr * 128 + m * 16 + hi4;
#pragma unroll
    for (int n = 0; n < 2; ++n) {
      const int gcol = bn * 128 + wc * 32 + n * 16 + fr;
      const float bb1 = b1v[gcol];
      const float bb2 = b2v[gcol];
#pragma unroll
      for (int i = 0; i < 4; ++i) {
        float u = acc1[m][n][i] + bb1;
        float g = acc2[m][n][i] + bb2;
        float r = (u / (1.f + __expf(-u))) * g;   // silu(u)*g
        if (MODE >= 2) r = (r > 0.f) ? (r + 1.f) : __expf(r);  // elu+1
        if (MODE == 3) r *= mask[grow0 + i];
        Out[(size_t)(grow0 + i) * D_DIM + gcol] = f2b(r);
      }
    }
  }
}

// 256x256-tile single GEMM (banked) — output projection only.
// MODE 0: out fp32 = acc + bias.
template<int MODE>
__global__ __launch_bounds__(512)
void gemm256(const short* __restrict__ A, const short* __restrict__ W,
             const float* __restrict__ bias, const short* __restrict__ U,
             const float* __restrict__ mask, void* __restrict__ OutV)
{
  __shared__ short lsA[2][256 * 64];
  __shared__ short lsB[2][256 * 64];
  const int t = threadIdx.x;            // 0..511
  const int lane = t & 63, w = t >> 6;  // 8 waves
  const int wr = w >> 2, wc = w & 3;    // 2 x 4 wave grid
  const int fr = lane & 15;
  const int kq = lane >> 4;
  const int cswz = fr & 7;
  const int orig = blockIdx.x;
  const int swz = (orig & 7) * 32 + (orig >> 3);
  const int bn = swz & 3, bm = swz >> 2;

  const f32x4 z4 = {0.f, 0.f, 0.f, 0.f};
  f32x4 acc[8][4];
#pragma unroll
  for (int m = 0; m < 8; ++m)
#pragma unroll
    for (int n = 0; n < 4; ++n) acc[m][n] = z4;

  const short* Ab = A + (size_t)bm * 256 * D_DIM;
  const short* Wb = W + (size_t)bn * 256 * D_DIM;

#define STAGE256(bi, ks)                                                     \
  {                                                                          \
    _Pragma("unroll")                                                        \
    for (int p = 0; p < 4; ++p) {                                            \
      const int idx = p * 512 + t;                                           \
      const int row = idx >> 3;                                              \
      const int cs = (idx & 7) ^ (row & 7);                                  \
      const size_t off = (size_t)row * D_DIM + (ks) * 64 + (cs << 3);        \
      __builtin_amdgcn_global_load_lds((const AS1 void*)(Ab + off),          \
          (AS3 void*)((AS3 short*)&lsA[bi][0] + idx * 8), 16, 0, 0);         \
      __builtin_amdgcn_global_load_lds((const AS1 void*)(Wb + off),          \
          (AS3 void*)((AS3 short*)&lsB[bi][0] + idx * 8), 16, 0, 0);         \
    }                                                                        \
  }

  STAGE256(0, 0);
  for (int ks = 0; ks < 16; ++ks) {
    const int cur = ks & 1;
    if (ks + 1 < 16) {
      STAGE256(cur ^ 1, ks + 1);
      asm volatile("s_waitcnt vmcnt(8)" ::: "memory");
    } else {
      asm volatile("s_waitcnt vmcnt(0)" ::: "memory");
    }
    __builtin_amdgcn_s_barrier();
    __builtin_amdgcn_sched_barrier(0);
#pragma unroll
    for (int kk = 0; kk < 64; kk += 32) {
      const int cb = kk >> 3;
      const int pch = ((cb + kq) ^ cswz) << 3;
      short8 bfrag[4];
#pragma unroll
      for (int n = 0; n < 4; ++n)
        bfrag[n] = *(const short8*)&lsB[cur][(wc * 64 + n * 16 + fr) * 64 + pch];
#pragma unroll
      for (int m = 0; m < 8; ++m) {
        short8 af = *(const short8*)&lsA[cur][(wr * 128 + m * 16 + fr) * 64 + pch];
#pragma unroll
        for (int n = 0; n < 4; ++n)
          acc[m][n] = __builtin_amdgcn_mfma_f32_16x16x32_bf16(
              af, bfrag[n], acc[m][n], 0, 0, 0);
      }
    }
    __builtin_amdgcn_sched_barrier(0);
    __builtin_amdgcn_s_barrier();
  }
#undef STAGE256

  const int hi4 = (lane >> 4) << 2;
#pragma unroll
  for (int m = 0; m < 8; ++m) {
    const int grow0 = bm * 256 + wr * 128 + m * 16 + hi4;
#pragma unroll
    for (int n = 0; n < 4; ++n) {
      const int gcol = bn * 256 + wc * 64 + n * 16 + fr;
      const float bb = bias[gcol];
#pragma unroll
      for (int i = 0; i < 4; ++i) {
        const size_t o = (size_t)(grow0 + i) * D_DIM + gcol;
        if (MODE == 0) {
          ((float*)OutV)[o] = acc[m][n][i] + bb;
        } else {
          float g = acc[m][n][i] + bb;
          float u = b2f(U[o]);
          float r = (u / (1.f + __expf(-u))) * g;
          if (MODE >= 2) r = (r > 0.f) ? (r + 1.f) : __expf(r);
          if (MODE == 3) r *= mask[grow0 + i];
          ((short*)OutV)[o] = f2b(r);
        }
      }
    }
  }
}

// kv[bh] += phi_k[s,:].outer(v[s,:]) over an s-chunk of 512; also ksum.
// 64-row chunks + wave-parallel ksum (banked).
__global__ __launch_bounds__(256)
void kv_partial(const short* __restrict__ PK, const short* __restrict__ PV,
                float* __restrict__ KVP, float* __restrict__ KSP)
{
  __shared__ float lsK[64 * 68];
  __shared__ float lsV[64 * 68];
  __shared__ float lsS[256];
  const int t = threadIdx.x;
  const int bh = blockIdx.x;               // 0..63
  const int b = bh >> 4, h = bh & 15;
  const int s0 = blockIdx.y * 512;         // 8 chunks
  const int r0 = (t >> 4) * 4, c0 = (t & 15) * 4;
  const int srow = t >> 3, d0 = (t & 7) * 8;
  const int kc = t & 63, kr0 = (t >> 6) * 16;
  float acc[4][4] = {{0.f}};
  float ks = 0.f;
  const size_t gbase = ((size_t)b * S_LEN + s0 + srow) * D_DIM + h * DK_DIM + d0;
  for (int sc = 0; sc < 512; sc += 64) {
    const size_t g = gbase + (size_t)sc * D_DIM;
    short8 rk0 = *(const short8*)(PK + g);
    short8 rv0 = *(const short8*)(PV + g);
    short8 rk1 = *(const short8*)(PK + g + (size_t)32 * D_DIM);
    short8 rv1 = *(const short8*)(PV + g + (size_t)32 * D_DIM);
    __syncthreads();   // prior chunk's readers (incl. ksum) done
#pragma unroll
    for (int j = 0; j < 8; ++j) {
      lsK[srow * 68 + d0 + j] = b2f(rk0[j]);
      lsV[srow * 68 + d0 + j] = b2f(rv0[j]);
      lsK[(srow + 32) * 68 + d0 + j] = b2f(rk1[j]);
      lsV[(srow + 32) * 68 + d0 + j] = b2f(rv1[j]);
    }
    __syncthreads();
#pragma unroll 8
    for (int s = 0; s < 64; ++s) {
      f32x4 ak = *(const f32x4*)&lsK[s * 68 + r0];
      f32x4 av = *(const f32x4*)&lsV[s * 68 + c0];
#pragma unroll
      for (int i = 0; i < 4; ++i)
#pragma unroll
        for (int j = 0; j < 4; ++j) acc[i][j] += ak[i] * av[j];
    }
#pragma unroll
    for (int i = 0; i < 16; ++i) ks += lsK[(kr0 + i) * 68 + kc];
  }
  const size_t po = ((size_t)bh * 8 + blockIdx.y) * 4096;
#pragma unroll
  for (int i = 0; i < 4; ++i)
#pragma unroll
    for (int j = 0; j < 4; ++j)
      KVP[po + (size_t)(r0 + i) * 64 + c0 + j] = acc[i][j];
  lsS[t] = ks;
  __syncthreads();
  if (t < 64)
    KSP[((size_t)bh * 8 + blockIdx.y) * 64 + t] =
        lsS[t] + lsS[64 + t] + lsS[128 + t] + lsS[192 + t];
}

__global__ __launch_bounds__(256)
void kv_reduce(const float* __restrict__ KVP, const float* __restrict__ KSP,
               float* __restrict__ KV, float* __restrict__ KS)
{
  const int bh = blockIdx.x;
  const int t = threadIdx.x;
#pragma unroll
  for (int c = 0; c < 4; ++c) {
    f32x4 a = {0.f, 0.f, 0.f, 0.f};
    for (int p = 0; p < 8; ++p)
      a += *(const f32x4*)&KVP[((size_t)bh * 8 + p) * 4096 + t * 16 + c * 4];
    *(f32x4*)&KV[(size_t)bh * 4096 + t * 16 + c * 4] = a;
  }
  if (t < 64) {
    float a = 0.f;
    for (int p = 0; p < 8; ++p) a += KSP[((size_t)bh * 8 + p) * 64 + t];
    KS[(size_t)bh * 64 + t] = a;
  }
}

// attn[s,:] = (phi_q[s,:] @ kv) / (phi_q[s,:].ksum + eps); 64 s-rows/block.
__global__ __launch_bounds__(256)
void attn_k(const short* __restrict__ PQ, const float* __restrict__ KV,
            const float* __restrict__ KS, short* __restrict__ ATT)
{
  __shared__ float lsKV[4096];
  __shared__ float lsQ[64 * 65];
  __shared__ float lsS[64];
  const int t = threadIdx.x;
  const int bh = blockIdx.x >> 6;
  const int ch = blockIdx.x & 63;
  const int b = bh >> 4, h = bh & 15;
  const int s0 = ch * 64;
#pragma unroll
  for (int c = 0; c < 4; ++c)
    *(f32x4*)&lsKV[t * 16 + c * 4] =
        *(const f32x4*)&KV[(size_t)bh * 4096 + t * 16 + c * 4];
  if (t < 64) lsS[t] = KS[(size_t)bh * 64 + t];
  const int qr = t >> 2, qd = (t & 3) * 16;
  const size_t gq = ((size_t)b * S_LEN + s0 + qr) * D_DIM + h * DK_DIM + qd;
  short8 q0 = *(const short8*)(PQ + gq);
  short8 q1 = *(const short8*)(PQ + gq + 8);
#pragma unroll
  for (int j = 0; j < 8; ++j) {
    lsQ[qr * 65 + qd + j] = b2f(q0[j]);
    lsQ[qr * 65 + qd + 8 + j] = b2f(q1[j]);
  }
  __syncthreads();
  float num[16] = {0.f};
  float z = 0.f;
#pragma unroll 4
  for (int k = 0; k < 64; ++k) {
    const float q = lsQ[qr * 65 + k];
    z += q * lsS[k];
#pragma unroll
    for (int c = 0; c < 4; ++c) {
      f32x4 kv4 = *(const f32x4*)&lsKV[k * 64 + qd + c * 4];
#pragma unroll
      for (int j = 0; j < 4; ++j) num[c * 4 + j] += q * kv4[j];
    }
  }
  const float inv = 1.f / (z + 1e-6f);
  short8 o0, o1;
#pragma unroll
  for (int j = 0; j < 8; ++j) {
    o0[j] = f2b(num[j] * inv);
    o1[j] = f2b(num[j + 8] * inv);
  }
  short* op = ATT + gq;
  *(short8*)op = o0;
  *(short8*)(op + 8) = o1;
}

extern "C" void kernel_launch(void* const* d_in, const int* in_sizes, int n_in,
                              void* d_out, int out_size, void* d_ws, size_t ws_size,
                              hipStream_t stream)
{
  (void)in_sizes; (void)n_in; (void)out_size; (void)ws_size;
  const float* query = (const float*)d_in[0];
  const float* key   = (const float*)d_in[1];
  const float* value = (const float*)d_in[2];
  const float* maskp = (const float*)d_in[3];
  const float* q_w1 = (const float*)d_in[4];
  const float* q_b1 = (const float*)d_in[5];
  const float* q_w2 = (const float*)d_in[6];
  const float* q_b2 = (const float*)d_in[7];
  const float* k_w1 = (const float*)d_in[8];
  const float* k_b1 = (const float*)d_in[9];
  const float* k_w2 = (const float*)d_in[10];
  const float* k_b2 = (const float*)d_in[11];
  const float* v_w1 = (const float*)d_in[12];
  const float* v_b1 = (const float*)d_in[13];
  const float* v_w2 = (const float*)d_in[14];
  const float* v_b2 = (const float*)d_in[15];
  const float* out_w = (const float*)d_in[16];
  const float* out_b = (const float*)d_in[17];

  // Workspace (~87.4 MiB, same layout as the passing rounds).
  char* ws = (char*)d_ws;
  const size_t ACT = (size_t)N_TOK * D_DIM * sizeof(short);     // 32 MiB
  const size_t WSZ = (size_t)D_DIM * D_DIM * sizeof(short);     // 2 MiB
  short* PHIK = (short*)(ws);
  short* Vbuf = (short*)(ws + ACT);
  float* KVP  = (float*)(ws + 2 * ACT);                          // 8 MiB
  float* KSP  = (float*)(ws + 2 * ACT + 8388608);                // 128 KiB
  float* KV   = (float*)(ws + 2 * ACT + 8388608 + 131072);       // 1 MiB
  float* KS   = (float*)(ws + 2 * ACT + 8388608 + 131072 + 1048576); // 16 KiB
  short* WB   = (short*)(ws + 2 * ACT + 8388608 + 131072 + 1048576 + 16384);
  short* wq1 = WB;                 short* wq2 = WB + 1 * (WSZ / 2);
  short* wk1 = WB + 2 * (WSZ / 2); short* wk2 = WB + 3 * (WSZ / 2);
  short* wv1 = WB + 4 * (WSZ / 2); short* wv2 = WB + 5 * (WSZ / 2);
  short* wout = WB + 6 * (WSZ / 2);
  // Buffer aliasing plan (all lifetimes audited):
  //   ABq = d_out upper 32 MiB (dead after gemm_dual<2>)
  //   ABk = Vbuf            (dead after gemm_dual<3>; Vbuf rewritten by
  //                          gemm_dual<1> afterwards)
  //   ABv = d_out upper     (reused after dual(q) freed it)
  //   PHIQ = d_out lower    (dead after attn_k; final gemm256 overwrites)
  //   ATT  = Vbuf           (phi_v dead after kv_partial)
  short* PHIQ = (short*)d_out;
  short* ABq  = (short*)d_out + (size_t)N_TOK * D_DIM;
  short* ABk  = Vbuf;
  short* ABv  = ABq;
  short* ATT  = Vbuf;

  dim3 gb(256);
  // One launch: 7 weights + query + key -> bf16 (39936 blocks).
  cvt_all<<<39936, gb, 0, stream>>>(q_w1, q_w2, k_w1, k_w2, v_w1, v_w2,
                                    out_w, WB, query, ABq, key, ABk);

  // fused dual projections (u and g in one pass; u stays fp32 in-register)
  gemm_dual<2><<<512, 512, 0, stream>>>(ABq, wq1, q_b1, wq2, q_b2,
                                        nullptr, PHIQ);
  gemm_dual<3><<<512, 512, 0, stream>>>(ABk, wk1, k_b1, wk2, k_b2,
                                        maskp, PHIK);
  cvt_a<<<16384, gb, 0, stream>>>(value, ABv);
  gemm_dual<1><<<512, 512, 0, stream>>>(ABv, wv1, v_b1, wv2, v_b2,
                                        nullptr, Vbuf);
  // linear attention core
  kv_partial<<<dim3(64, 8), gb, 0, stream>>>(PHIK, Vbuf, KVP, KSP);
  kv_reduce<<<64, gb, 0, stream>>>(KVP, KSP, KV, KS);
  attn_k<<<4096, gb, 0, stream>>>(PHIQ, KV, KS, ATT);
  // output projection (fp32 out)
  gemm256<0><<<256, 512, 0, stream>>>(ATT, wout, out_b, nullptr, nullptr,
                                      (float*)d_out);
}